// Round 1
// baseline (1347.139 us; speedup 1.0000x reference)
//
#include <hip/hip_runtime.h>
#include <hip/hip_bf16.h>

typedef unsigned short u16;
typedef __attribute__((ext_vector_type(8))) short short8;
typedef __attribute__((ext_vector_type(4))) float f32x4;
typedef __attribute__((ext_vector_type(4))) u16 u16x4;
typedef __attribute__((ext_vector_type(8))) u16 u16x8;

#define T_TOK 8192
#define NSLOT 16384
#define H_DIM 1024
#define I_DIM 4096
#define N_EXP 8
#define MAXTILES 144

// ws layout (bytes)
#define O_META 0                                    // int meta[512]
#define O_ETOK 4096                                 // int[16384]
#define O_EW   (O_ETOK + NSLOT * 4)                 // float[16384]
#define O_XB   (256 * 1024)                         // bf16 [8192][1024]
#define O_WIN  (O_XB + (size_t)T_TOK * H_DIM * 2)   // bf16 [8][4096][1024] (W_in^T)
#define O_WV   (O_WIN + (size_t)N_EXP * I_DIM * H_DIM * 2)
#define O_WOUT (O_WV + (size_t)N_EXP * I_DIM * H_DIM * 2) // bf16 [8][1024][4096] (W_out^T)
#define O_G    (O_WOUT + (size_t)N_EXP * H_DIM * I_DIM * 2) // bf16 [144*128][4096]
// total ≈ 352.3 MiB

// meta int layout: [0]=tileCount, [16..160)=tileExpert, [160..304)=rowStart,
// [304..448)=rowEnd, [448..456)=cursors

__device__ __forceinline__ u16 f2bf(float f) {
  union { float f; unsigned u; } v; v.f = f;
  unsigned r = v.u + 0x7FFFu + ((v.u >> 16) & 1u);   // RNE
  return (u16)(r >> 16);
}

#define GLL(g, l) __builtin_amdgcn_global_load_lds( \
    (const __attribute__((address_space(1))) void*)(g), \
    (__attribute__((address_space(3))) void*)(l), 16, 0, 0)

#define MFMA16(a, b, c) __builtin_amdgcn_mfma_f32_16x16x32_bf16(a, b, c, 0, 0, 0)

__global__ void route_count(const int* __restrict__ sel, int* __restrict__ meta) {
  __shared__ int cnt[N_EXP];
  const int tid = threadIdx.x;
  if (tid < N_EXP) cnt[tid] = 0;
  __syncthreads();
  for (int i = tid; i < NSLOT; i += 256) atomicAdd(&cnt[sel[i]], 1);
  __syncthreads();
  if (tid == 0) {
    int run = 0, tc = 0;
    for (int e = 0; e < N_EXP; ++e) {
      const int c = cnt[e];
      meta[448 + e] = run;                 // fill cursor
      const int nt = (c + 127) >> 7;
      for (int t = 0; t < nt; ++t) {
        meta[16 + tc] = e;
        meta[160 + tc] = run + t * 128;
        int end = run + t * 128 + 128;
        if (end > run + c) end = run + c;
        meta[304 + tc] = end;
        ++tc;
      }
      run += c;
    }
    meta[0] = tc;
  }
}

__global__ void route_fill(const int* __restrict__ sel, const float* __restrict__ rw,
                           int* __restrict__ meta, int* __restrict__ etok,
                           float* __restrict__ ew) {
  const int i = blockIdx.x * 256 + threadIdx.x;
  if (i >= NSLOT) return;
  const int e = sel[i];
  const int pos = atomicAdd(&meta[448 + e], 1);
  etok[pos] = i >> 1;      // token id (K=2)
  ew[pos] = rw[i];
}

__global__ void conv_x(const float* __restrict__ x, u16* __restrict__ xb) {
  const size_t i = ((size_t)blockIdx.x * 256 + threadIdx.x) * 4;
  const float4 v = *(const float4*)&x[i];
  u16x4 o;
  o.x = f2bf(v.x); o.y = f2bf(v.y); o.z = f2bf(v.z); o.w = f2bf(v.w);
  *(u16x4*)&xb[i] = o;
}

// src [nmat][R][C] f32  ->  dst [nmat][C][R] bf16
__global__ void transp_conv(const float* __restrict__ src, u16* __restrict__ dst,
                            int R, int C) {
  __shared__ float t[64][65];
  const int tid = threadIdx.x;
  const int mat = blockIdx.z;
  const int rb = blockIdx.y * 64, cb = blockIdx.x * 64;
  const float* s = src + (size_t)mat * R * C + (size_t)rb * C + cb;
#pragma unroll
  for (int it = 0; it < 4; ++it) {
    const int r = it * 16 + (tid >> 4);
    const int c = (tid & 15) * 4;
    const float4 v = *(const float4*)&s[(size_t)r * C + c];
    t[r][c] = v.x; t[r][c + 1] = v.y; t[r][c + 2] = v.z; t[r][c + 3] = v.w;
  }
  __syncthreads();
  u16* d = dst + (size_t)mat * R * C + (size_t)cb * R + rb;
#pragma unroll
  for (int it = 0; it < 2; ++it) {
    const int oc = it * 32 + (tid >> 3);
    const int j0 = (tid & 7) * 8;
    u16x8 o;
#pragma unroll
    for (int j = 0; j < 8; ++j) o[j] = f2bf(t[j0 + j][oc]);
    *(u16x8*)&d[(size_t)oc * R + j0] = o;
  }
}

// GEMM1: G = gelu(Xg @ W_in^T') * (Xg @ W_v^T'), 128x128 tile, BK=32
__global__ __launch_bounds__(256) void gemm1(
    const u16* __restrict__ Xb, const u16* __restrict__ Wi,
    const u16* __restrict__ Wv, u16* __restrict__ Gout,
    const int* __restrict__ meta, const int* __restrict__ etok) {
  const int tile = blockIdx.y;
  if (tile >= meta[0]) return;
  const int e  = meta[16 + tile];
  const int r0 = meta[160 + tile];
  const int r1 = meta[304 + tile];
  const int n0 = blockIdx.x << 7;

  __shared__ __align__(16) u16 As[2][4096];
  __shared__ __align__(16) u16 Bi[2][4096];
  __shared__ __align__(16) u16 Bv[2][4096];

  const int tid = threadIdx.x;
  const int t0 = tid, t1 = tid + 256;
  const int rA0 = t0 >> 2, rA1 = t1 >> 2;
  const int sc0 = ((t0 & 3) ^ (rA0 & 3)) << 3;   // source-chunk XOR swizzle (elems)
  const int sc1 = ((t1 & 3) ^ (rA1 & 3)) << 3;
  int ia0 = r0 + rA0; if (ia0 >= r1) ia0 = r0;   // clamp padded rows
  int ia1 = r0 + rA1; if (ia1 >= r1) ia1 = r0;
  const u16* gA0 = Xb + (size_t)etok[ia0] * H_DIM + sc0;
  const u16* gA1 = Xb + (size_t)etok[ia1] * H_DIM + sc1;
  const size_t wb = ((size_t)e * I_DIM + n0) * H_DIM;
  const u16* gBi0 = Wi + wb + (size_t)rA0 * H_DIM + sc0;
  const u16* gBi1 = Wi + wb + (size_t)rA1 * H_DIM + sc1;
  const u16* gBv0 = Wv + wb + (size_t)rA0 * H_DIM + sc0;
  const u16* gBv1 = Wv + wb + (size_t)rA1 * H_DIM + sc1;

  const int lane = tid & 63;
  const int wid = tid >> 6;
  const int wm = (wid >> 1) << 6, wn = (wid & 1) << 6;
  const int lr = lane & 15, q = lane >> 4;
  const int cq = (q ^ (lr & 3)) << 3;
  int aoff[4], boff[4];
#pragma unroll
  for (int i = 0; i < 4; ++i) {
    aoff[i] = (wm + i * 16 + lr) * 32 + cq;
    boff[i] = (wn + i * 16 + lr) * 32 + cq;
  }

  f32x4 ci[4][4], cv[4][4];
#pragma unroll
  for (int i = 0; i < 4; ++i)
#pragma unroll
    for (int j = 0; j < 4; ++j) { ci[i][j] = (f32x4)0.0f; cv[i][j] = (f32x4)0.0f; }

#define STAGE1(b, kt) do { const int ko = (kt) << 5;                      \
    GLL(gA0 + ko, &As[b][t0 * 8]);  GLL(gA1 + ko, &As[b][t1 * 8]);        \
    GLL(gBi0 + ko, &Bi[b][t0 * 8]); GLL(gBi1 + ko, &Bi[b][t1 * 8]);       \
    GLL(gBv0 + ko, &Bv[b][t0 * 8]); GLL(gBv1 + ko, &Bv[b][t1 * 8]); } while (0)

  STAGE1(0, 0);
  __syncthreads();
  int buf = 0;
  for (int kt = 0; kt < H_DIM / 32; ++kt) {
    if (kt + 1 < H_DIM / 32) STAGE1(buf ^ 1, kt + 1);
    short8 a[4], fi[4], fv[4];
#pragma unroll
    for (int i = 0; i < 4; ++i) a[i] = *(const short8*)&As[buf][aoff[i]];
#pragma unroll
    for (int j = 0; j < 4; ++j) fi[j] = *(const short8*)&Bi[buf][boff[j]];
#pragma unroll
    for (int j = 0; j < 4; ++j) fv[j] = *(const short8*)&Bv[buf][boff[j]];
#pragma unroll
    for (int i = 0; i < 4; ++i)
#pragma unroll
      for (int j = 0; j < 4; ++j) {
        ci[i][j] = MFMA16(a[i], fi[j], ci[i][j]);
        cv[i][j] = MFMA16(a[i], fv[j], cv[i][j]);
      }
    __syncthreads();
    buf ^= 1;
  }

  u16* gbase = Gout + (size_t)tile * 128 * I_DIM;
#pragma unroll
  for (int i = 0; i < 4; ++i)
#pragma unroll
    for (int t = 0; t < 4; ++t) {
      const int row = wm + i * 16 + q * 4 + t;
      u16* grow = gbase + (size_t)row * I_DIM + n0 + wn + lr;
#pragma unroll
      for (int j = 0; j < 4; ++j) {
        const float x = ci[i][j][t];
        const float g = 0.5f * x *
            (1.0f + tanhf(0.7978845608f * (x + 0.044715f * x * x * x)));
        grow[j * 16] = f2bf(g * cv[i][j][t]);
      }
    }
}

// GEMM2: out[tok] += w * (G @ W_out^T'), 128x128 tile, BK=32
__global__ __launch_bounds__(256) void gemm2(
    const u16* __restrict__ Gin, const u16* __restrict__ Wo,
    float* __restrict__ out, const int* __restrict__ meta,
    const int* __restrict__ etok, const float* __restrict__ ew) {
  const int tile = blockIdx.y;
  if (tile >= meta[0]) return;
  const int e  = meta[16 + tile];
  const int r0 = meta[160 + tile];
  const int r1 = meta[304 + tile];
  const int n0 = blockIdx.x << 7;

  __shared__ __align__(16) u16 As[2][4096];
  __shared__ __align__(16) u16 Bs[2][4096];
  __shared__ int tok_s[128];
  __shared__ float w_s[128];

  const int tid = threadIdx.x;
  if (tid < 128) {
    const int idx = r0 + tid;
    const bool v = idx < r1;
    tok_s[tid] = v ? etok[idx] : -1;
    w_s[tid] = v ? ew[idx] : 0.0f;
  }

  const int t0 = tid, t1 = tid + 256;
  const int rA0 = t0 >> 2, rA1 = t1 >> 2;
  const int sc0 = ((t0 & 3) ^ (rA0 & 3)) << 3;
  const int sc1 = ((t1 & 3) ^ (rA1 & 3)) << 3;
  const u16* gA0 = Gin + ((size_t)tile * 128 + rA0) * I_DIM + sc0;
  const u16* gA1 = Gin + ((size_t)tile * 128 + rA1) * I_DIM + sc1;
  const size_t wb = (size_t)e * H_DIM * I_DIM;
  const u16* gB0 = Wo + wb + (size_t)(n0 + rA0) * I_DIM + sc0;
  const u16* gB1 = Wo + wb + (size_t)(n0 + rA1) * I_DIM + sc1;

  const int lane = tid & 63;
  const int wid = tid >> 6;
  const int wm = (wid >> 1) << 6, wn = (wid & 1) << 6;
  const int lr = lane & 15, q = lane >> 4;
  const int cq = (q ^ (lr & 3)) << 3;
  int aoff[4], boff[4];
#pragma unroll
  for (int i = 0; i < 4; ++i) {
    aoff[i] = (wm + i * 16 + lr) * 32 + cq;
    boff[i] = (wn + i * 16 + lr) * 32 + cq;
  }

  f32x4 c[4][4];
#pragma unroll
  for (int i = 0; i < 4; ++i)
#pragma unroll
    for (int j = 0; j < 4; ++j) c[i][j] = (f32x4)0.0f;

#define STAGE2(b, kt) do { const int ko = (kt) << 5;                  \
    GLL(gA0 + ko, &As[b][t0 * 8]); GLL(gA1 + ko, &As[b][t1 * 8]);     \
    GLL(gB0 + ko, &Bs[b][t0 * 8]); GLL(gB1 + ko, &Bs[b][t1 * 8]); } while (0)

  STAGE2(0, 0);
  __syncthreads();
  int buf = 0;
  for (int kt = 0; kt < I_DIM / 32; ++kt) {
    if (kt + 1 < I_DIM / 32) STAGE2(buf ^ 1, kt + 1);
    short8 a[4], b_[4];
#pragma unroll
    for (int i = 0; i < 4; ++i) a[i] = *(const short8*)&As[buf][aoff[i]];
#pragma unroll
    for (int j = 0; j < 4; ++j) b_[j] = *(const short8*)&Bs[buf][boff[j]];
#pragma unroll
    for (int i = 0; i < 4; ++i)
#pragma unroll
      for (int j = 0; j < 4; ++j) c[i][j] = MFMA16(a[i], b_[j], c[i][j]);
    __syncthreads();
    buf ^= 1;
  }

#pragma unroll
  for (int i = 0; i < 4; ++i)
#pragma unroll
    for (int t = 0; t < 4; ++t) {
      const int row = wm + i * 16 + q * 4 + t;
      const int tk = tok_s[row];
      if (tk >= 0) {
        const float wgt = w_s[row];
        float* orow = out + (size_t)tk * H_DIM + n0 + wn + lr;
#pragma unroll
        for (int j = 0; j < 4; ++j) atomicAdd(&orow[j * 16], wgt * c[i][j][t]);
      }
    }
}

extern "C" void kernel_launch(void* const* d_in, const int* in_sizes, int n_in,
                              void* d_out, int out_size, void* d_ws, size_t ws_size,
                              hipStream_t stream) {
  const float* hs   = (const float*)d_in[0];
  const float* rw   = (const float*)d_in[1];
  const int*   sel  = (const int*)d_in[2];
  const float* w_in = (const float*)d_in[3];
  const float* w_v  = (const float*)d_in[4];
  const float* w_out = (const float*)d_in[5];
  float* out = (float*)d_out;
  char* ws = (char*)d_ws;
  int* meta  = (int*)(ws + O_META);
  int* etok  = (int*)(ws + O_ETOK);
  float* ew  = (float*)(ws + O_EW);
  u16* xb = (u16*)(ws + O_XB);
  u16* wi = (u16*)(ws + O_WIN);
  u16* wv = (u16*)(ws + O_WV);
  u16* wo = (u16*)(ws + O_WOUT);
  u16* g  = (u16*)(ws + O_G);

  hipMemsetAsync(out, 0, (size_t)T_TOK * H_DIM * sizeof(float), stream);
  route_count<<<1, 256, 0, stream>>>(sel, meta);
  route_fill<<<NSLOT / 256, 256, 0, stream>>>(sel, rw, meta, etok, ew);
  conv_x<<<(T_TOK * H_DIM / 4) / 256, 256, 0, stream>>>(hs, xb);
  transp_conv<<<dim3(I_DIM / 64, H_DIM / 64, N_EXP), 256, 0, stream>>>(w_in, wi, H_DIM, I_DIM);
  transp_conv<<<dim3(I_DIM / 64, H_DIM / 64, N_EXP), 256, 0, stream>>>(w_v, wv, H_DIM, I_DIM);
  transp_conv<<<dim3(H_DIM / 64, I_DIM / 64, N_EXP), 256, 0, stream>>>(w_out, wo, I_DIM, H_DIM);
  gemm1<<<dim3(I_DIM / 128, MAXTILES), 256, 0, stream>>>(xb, wi, wv, g, meta, etok);
  gemm2<<<dim3(H_DIM / 128, MAXTILES), 256, 0, stream>>>(g, wo, out, meta, etok, ew);
}

// Round 5
// 1175.757 us; speedup vs baseline: 1.1458x; 1.1458x over previous
//
#include <hip/hip_runtime.h>
#include <hip/hip_bf16.h>

typedef unsigned short u16;
typedef __attribute__((ext_vector_type(8))) short short8;
typedef __attribute__((ext_vector_type(4))) float f32x4;
typedef __attribute__((ext_vector_type(4))) u16 u16x4;
typedef __attribute__((ext_vector_type(8))) u16 u16x8;

#define T_TOK 8192
#define NSLOT 16384
#define H_DIM 1024
#define I_DIM 4096
#define N_CAT 8192   // 2*I, Wi/Wv interleaved in 16-col blocks
#define N_EXP 8
#define MAXTILES 144

// ws layout (bytes)
#define O_META 0                                        // int meta[512]
#define O_ETOK 4096                                     // int[16384]
#define O_EW   (O_ETOK + NSLOT * 4)                     // float[16384]
#define O_INV  (O_EW + NSLOT * 4)                       // int[16384] slot->pos
#define O_XB   (256 * 1024)                             // bf16 [8192][1024]
#define O_WCAT (O_XB + (size_t)T_TOK * H_DIM * 2)       // bf16 [8][8192][1024]
#define O_WOUT (O_WCAT + (size_t)N_EXP * N_CAT * H_DIM * 2) // bf16 [8][1024][4096]
#define O_G    (O_WOUT + (size_t)N_EXP * I_DIM * H_DIM * 2) // bf16 [144*128][4096]
#define O_OS   O_WCAT   // f32 [16384][1024]; aliases Wcat (dead after gemm1)
// total ≈ 352.3 MiB

// meta: [0]=tileCount, [16..160)=tileExpert, [160..304)=rowStart,
// [304..448)=rowEnd, [448..456)=cursors

__device__ __forceinline__ u16 f2bf(float f) {
  union { float f; unsigned u; } v; v.f = f;
  unsigned r = v.u + 0x7FFFu + ((v.u >> 16) & 1u);   // RNE
  return (u16)(r >> 16);
}

#define GLL(g, l) __builtin_amdgcn_global_load_lds( \
    (const __attribute__((address_space(1))) void*)(g), \
    (__attribute__((address_space(3))) void*)(l), 16, 0, 0)

#define MFMA16(a, b, c) __builtin_amdgcn_mfma_f32_16x16x32_bf16(a, b, c, 0, 0, 0)

__global__ void route_count(const int* __restrict__ sel, int* __restrict__ meta) {
  __shared__ int cnt[N_EXP];
  const int tid = threadIdx.x;
  if (tid < N_EXP) cnt[tid] = 0;
  __syncthreads();
  for (int i = tid; i < NSLOT; i += 256) atomicAdd(&cnt[sel[i]], 1);
  __syncthreads();
  if (tid == 0) {
    int run = 0, tc = 0;
    for (int e = 0; e < N_EXP; ++e) {
      const int c = cnt[e];
      meta[448 + e] = run;
      const int nt = (c + 127) >> 7;
      for (int t = 0; t < nt; ++t) {
        meta[16 + tc] = e;
        meta[160 + tc] = run + t * 128;
        int end = run + t * 128 + 128;
        if (end > run + c) end = run + c;
        meta[304 + tc] = end;
        ++tc;
      }
      run += c;
    }
    meta[0] = tc;
  }
}

__global__ void route_fill(const int* __restrict__ sel, const float* __restrict__ rw,
                           int* __restrict__ meta, int* __restrict__ etok,
                           float* __restrict__ ew, int* __restrict__ inv) {
  const int i = blockIdx.x * 256 + threadIdx.x;
  if (i >= NSLOT) return;
  const int e = sel[i];
  const int pos = atomicAdd(&meta[448 + e], 1);
  etok[pos] = i >> 1;      // token id (K=2)
  ew[pos] = rw[i];
  inv[i] = pos;
}

__global__ void conv_x(const float* __restrict__ x, u16* __restrict__ xb) {
  const size_t i = ((size_t)blockIdx.x * 256 + threadIdx.x) * 4;
  const float4 v = *(const float4*)&x[i];
  u16x4 o;
  o.x = f2bf(v.x); o.y = f2bf(v.y); o.z = f2bf(v.z); o.w = f2bf(v.w);
  *(u16x4*)&xb[i] = o;
}

// src [nmat][R][C] f32 -> transpose+convert to bf16.
// mode 0: Wi -> Wcat row ((c>>4)<<5)|(c&15)         (dst [nmat][2C][R])
// mode 1: Wv -> Wcat row ((c>>4)<<5)|16|(c&15)
// mode 2: plain transpose (dst [nmat][C][R])
__global__ void transp_conv(const float* __restrict__ src, u16* __restrict__ dst,
                            int R, int C, int mode) {
  __shared__ float t[64][65];
  const int tid = threadIdx.x;
  const int mat = blockIdx.z;
  const int rb = blockIdx.y * 64, cb = blockIdx.x * 64;
  const float* s = src + (size_t)mat * R * C + (size_t)rb * C + cb;
#pragma unroll
  for (int it = 0; it < 4; ++it) {
    const int r = it * 16 + (tid >> 4);
    const int c = (tid & 15) * 4;
    const float4 v = *(const float4*)&s[(size_t)r * C + c];
    t[r][c] = v.x; t[r][c + 1] = v.y; t[r][c + 2] = v.z; t[r][c + 3] = v.w;
  }
  __syncthreads();
  const size_t dstride = (mode == 2) ? (size_t)R * C : 2 * (size_t)R * C;
  u16* dd = dst + (size_t)mat * dstride;
#pragma unroll
  for (int it = 0; it < 2; ++it) {
    const int ocl = it * 32 + (tid >> 3);
    const int oc = cb + ocl;
    const int mrow = (mode == 2) ? oc : (((oc >> 4) << 5) | (mode << 4) | (oc & 15));
    const int j0 = (tid & 7) * 8;
    u16x8 o;
#pragma unroll
    for (int j = 0; j < 8; ++j) o[j] = f2bf(t[j0 + j][oc - cb]);
    *(u16x8*)&dd[(size_t)mrow * R + rb + j0] = o;
  }
}

// GEMM1: C = Xg @ Wcat^T-layout, 128x128 tile, BK=32; epilogue pairs
// (even,odd) 16-col blocks -> G = gelu(ci)*cv  [tile*128+row][I_DIM]
__global__ __launch_bounds__(256) void gemm1(
    const u16* __restrict__ Xb, const u16* __restrict__ Wc,
    u16* __restrict__ Gout, const int* __restrict__ meta,
    const int* __restrict__ etok) {
  const int tile = blockIdx.y;
  if (tile >= meta[0]) return;
  const int e  = meta[16 + tile];
  const int r0 = meta[160 + tile];
  const int r1 = meta[304 + tile];
  const int n0 = blockIdx.x << 7;   // over N_CAT=8192

  __shared__ __align__(16) u16 As[2][4096];
  __shared__ __align__(16) u16 Bs[2][4096];

  const int tid = threadIdx.x;
  const int t0 = tid, t1 = tid + 256;
  const int rA0 = t0 >> 2, rA1 = t1 >> 2;
  const int sc0 = ((t0 & 3) ^ (rA0 & 3)) << 3;
  const int sc1 = ((t1 & 3) ^ (rA1 & 3)) << 3;
  int ia0 = r0 + rA0; if (ia0 >= r1) ia0 = r0;
  int ia1 = r0 + rA1; if (ia1 >= r1) ia1 = r0;
  const u16* gA0 = Xb + (size_t)etok[ia0] * H_DIM + sc0;
  const u16* gA1 = Xb + (size_t)etok[ia1] * H_DIM + sc1;
  const u16* gB0 = Wc + ((size_t)e * N_CAT + n0 + rA0) * H_DIM + sc0;
  const u16* gB1 = Wc + ((size_t)e * N_CAT + n0 + rA1) * H_DIM + sc1;

  const int lane = tid & 63;
  const int wid = tid >> 6;
  const int wm = (wid >> 1) << 6, wn = (wid & 1) << 6;
  const int lr = lane & 15, q = lane >> 4;
  const int cq = (q ^ (lr & 3)) << 3;
  int aoff[4], boff[4];
#pragma unroll
  for (int i = 0; i < 4; ++i) {
    aoff[i] = (wm + i * 16 + lr) * 32 + cq;
    boff[i] = (wn + i * 16 + lr) * 32 + cq;
  }

  f32x4 c[4][4];
#pragma unroll
  for (int i = 0; i < 4; ++i)
#pragma unroll
    for (int j = 0; j < 4; ++j) c[i][j] = (f32x4)0.0f;

#define STAGE1(b, kt) do { const int ko = (kt) << 5;                  \
    GLL(gA0 + ko, &As[b][t0 * 8]); GLL(gA1 + ko, &As[b][t1 * 8]);     \
    GLL(gB0 + ko, &Bs[b][t0 * 8]); GLL(gB1 + ko, &Bs[b][t1 * 8]); } while (0)

  STAGE1(0, 0);
  __syncthreads();
  int buf = 0;
  for (int kt = 0; kt < H_DIM / 32; ++kt) {
    if (kt + 1 < H_DIM / 32) STAGE1(buf ^ 1, kt + 1);
    short8 a[4], b_[4];
#pragma unroll
    for (int i = 0; i < 4; ++i) a[i] = *(const short8*)&As[buf][aoff[i]];
#pragma unroll
    for (int j = 0; j < 4; ++j) b_[j] = *(const short8*)&Bs[buf][boff[j]];
#pragma unroll
    for (int i = 0; i < 4; ++i)
#pragma unroll
      for (int j = 0; j < 4; ++j) c[i][j] = MFMA16(a[i], b_[j], c[i][j]);
    __syncthreads();
    buf ^= 1;
  }

  // epilogue: j-tile pairs (2p, 2p+1) = (Wi, Wv) for G col gcb + p*16 + lr
  u16* gb = Gout + (size_t)tile * 128 * I_DIM;
  const int gcb = (n0 + wn) >> 1;
#pragma unroll
  for (int i = 0; i < 4; ++i)
#pragma unroll
    for (int t = 0; t < 4; ++t) {
      const int row = wm + i * 16 + q * 4 + t;
      u16* grow = gb + (size_t)row * I_DIM + gcb + lr;
#pragma unroll
      for (int p = 0; p < 2; ++p) {
        const float x = c[i][2 * p][t];
        const float v = c[i][2 * p + 1][t];
        const float u = 0.7978845608f * (x + 0.044715f * x * x * x);
        const float texp = __expf(2.0f * u);
        const float th = 1.0f - 2.0f / (texp + 1.0f);   // tanh(u), inf-safe
        grow[p * 16] = f2bf(0.5f * x * (1.0f + th) * v);
      }
    }
}

// GEMM2: Os[slot] = G @ W_out^T', 128x128 tile, BK=32, plain f32 stores
__global__ __launch_bounds__(256) void gemm2(
    const u16* __restrict__ Gin, const u16* __restrict__ Wo,
    float* __restrict__ Os, const int* __restrict__ meta) {
  const int tile = blockIdx.y;
  if (tile >= meta[0]) return;
  const int e  = meta[16 + tile];
  const int r0 = meta[160 + tile];
  const int r1 = meta[304 + tile];
  const int n0 = blockIdx.x << 7;

  __shared__ __align__(16) u16 As[2][4096];
  __shared__ __align__(16) u16 Bs[2][4096];

  const int tid = threadIdx.x;
  const int t0 = tid, t1 = tid + 256;
  const int rA0 = t0 >> 2, rA1 = t1 >> 2;
  const int sc0 = ((t0 & 3) ^ (rA0 & 3)) << 3;
  const int sc1 = ((t1 & 3) ^ (rA1 & 3)) << 3;
  const u16* gA0 = Gin + ((size_t)tile * 128 + rA0) * I_DIM + sc0;
  const u16* gA1 = Gin + ((size_t)tile * 128 + rA1) * I_DIM + sc1;
  const size_t wb = (size_t)e * H_DIM * I_DIM;
  const u16* gB0 = Wo + wb + (size_t)(n0 + rA0) * I_DIM + sc0;
  const u16* gB1 = Wo + wb + (size_t)(n0 + rA1) * I_DIM + sc1;

  const int lane = tid & 63;
  const int wid = tid >> 6;
  const int wm = (wid >> 1) << 6, wn = (wid & 1) << 6;
  const int lr = lane & 15, q = lane >> 4;
  const int cq = (q ^ (lr & 3)) << 3;
  int aoff[4], boff[4];
#pragma unroll
  for (int i = 0; i < 4; ++i) {
    aoff[i] = (wm + i * 16 + lr) * 32 + cq;
    boff[i] = (wn + i * 16 + lr) * 32 + cq;
  }

  f32x4 c[4][4];
#pragma unroll
  for (int i = 0; i < 4; ++i)
#pragma unroll
    for (int j = 0; j < 4; ++j) c[i][j] = (f32x4)0.0f;

#define STAGE2(b, kt) do { const int ko = (kt) << 5;                  \
    GLL(gA0 + ko, &As[b][t0 * 8]); GLL(gA1 + ko, &As[b][t1 * 8]);     \
    GLL(gB0 + ko, &Bs[b][t0 * 8]); GLL(gB1 + ko, &Bs[b][t1 * 8]); } while (0)

  STAGE2(0, 0);
  __syncthreads();
  int buf = 0;
  for (int kt = 0; kt < I_DIM / 32; ++kt) {
    if (kt + 1 < I_DIM / 32) STAGE2(buf ^ 1, kt + 1);
    short8 a[4], b_[4];
#pragma unroll
    for (int i = 0; i < 4; ++i) a[i] = *(const short8*)&As[buf][aoff[i]];
#pragma unroll
    for (int j = 0; j < 4; ++j) b_[j] = *(const short8*)&Bs[buf][boff[j]];
#pragma unroll
    for (int i = 0; i < 4; ++i)
#pragma unroll
      for (int j = 0; j < 4; ++j) c[i][j] = MFMA16(a[i], b_[j], c[i][j]);
    __syncthreads();
    buf ^= 1;
  }

#pragma unroll
  for (int i = 0; i < 4; ++i)
#pragma unroll
    for (int t = 0; t < 4; ++t) {
      const int row = wm + i * 16 + q * 4 + t;
      const int gp = r0 + row;
      if (gp < r1) {
        float* orow = Os + (size_t)gp * H_DIM + n0 + wn + lr;
#pragma unroll
        for (int j = 0; j < 4; ++j) orow[j * 16] = c[i][j][t];
      }
    }
}

// out[t] = w0*Os[p0] + w1*Os[p1]; one block per token
__global__ void combine(const float* __restrict__ Os, const int* __restrict__ inv,
                        const float* __restrict__ ew, float* __restrict__ out) {
  const int t = blockIdx.x;
  const int c4 = threadIdx.x * 4;
  const int p0 = inv[2 * t], p1 = inv[2 * t + 1];
  const float w0 = ew[p0], w1 = ew[p1];
  const float4 a = *(const float4*)&Os[(size_t)p0 * H_DIM + c4];
  const float4 b = *(const float4*)&Os[(size_t)p1 * H_DIM + c4];
  float4 o;
  o.x = w0 * a.x + w1 * b.x;
  o.y = w0 * a.y + w1 * b.y;
  o.z = w0 * a.z + w1 * b.z;
  o.w = w0 * a.w + w1 * b.w;
  *(float4*)&out[(size_t)t * H_DIM + c4] = o;
}

extern "C" void kernel_launch(void* const* d_in, const int* in_sizes, int n_in,
                              void* d_out, int out_size, void* d_ws, size_t ws_size,
                              hipStream_t stream) {
  const float* hs    = (const float*)d_in[0];
  const float* rw    = (const float*)d_in[1];
  const int*   sel   = (const int*)d_in[2];
  const float* w_in  = (const float*)d_in[3];
  const float* w_v   = (const float*)d_in[4];
  const float* w_out = (const float*)d_in[5];
  float* out = (float*)d_out;
  char* ws = (char*)d_ws;
  int* meta   = (int*)(ws + O_META);
  int* etok   = (int*)(ws + O_ETOK);
  float* ew   = (float*)(ws + O_EW);
  int* inv    = (int*)(ws + O_INV);
  u16* xb     = (u16*)(ws + O_XB);
  u16* wcat   = (u16*)(ws + O_WCAT);
  u16* wo     = (u16*)(ws + O_WOUT);
  u16* g      = (u16*)(ws + O_G);
  float* os   = (float*)(ws + O_OS);

  route_count<<<1, 256, 0, stream>>>(sel, meta);
  route_fill<<<NSLOT / 256, 256, 0, stream>>>(sel, rw, meta, etok, ew, inv);
  conv_x<<<(T_TOK * H_DIM / 4) / 256, 256, 0, stream>>>(hs, xb);
  transp_conv<<<dim3(I_DIM / 64, H_DIM / 64, N_EXP), 256, 0, stream>>>(w_in, wcat, H_DIM, I_DIM, 0);
  transp_conv<<<dim3(I_DIM / 64, H_DIM / 64, N_EXP), 256, 0, stream>>>(w_v, wcat, H_DIM, I_DIM, 1);
  transp_conv<<<dim3(H_DIM / 64, I_DIM / 64, N_EXP), 256, 0, stream>>>(w_out, wo, I_DIM, H_DIM, 2);
  gemm1<<<dim3(N_CAT / 128, MAXTILES), 256, 0, stream>>>(xb, wcat, g, meta, etok);
  gemm2<<<dim3(H_DIM / 128, MAXTILES), 256, 0, stream>>>(g, wo, os, meta);
  combine<<<T_TOK, 256, 0, stream>>>(os, inv, ew, out);
}

// Round 11
// 1153.878 us; speedup vs baseline: 1.1675x; 1.0190x over previous
//
#include <hip/hip_runtime.h>
#include <hip/hip_bf16.h>

typedef unsigned short u16;
typedef __attribute__((ext_vector_type(8))) short short8;
typedef __attribute__((ext_vector_type(4))) float f32x4;
typedef __attribute__((ext_vector_type(4))) u16 u16x4;
typedef __attribute__((ext_vector_type(8))) u16 u16x8;

#define T_TOK 8192
#define NSLOT 16384
#define H_DIM 1024
#define I_DIM 4096
#define N_CAT 8192   // 2*I, Wi/Wv interleaved in 16-col blocks
#define N_EXP 8
#define MAXTILES 144

// ws layout (bytes)
#define O_META 0                                        // int meta[512]
#define O_ETOK 4096                                     // int[16384]
#define O_EW   (O_ETOK + NSLOT * 4)                     // float[16384]
#define O_INV  (O_EW + NSLOT * 4)                       // int[16384] slot->pos
#define O_XB   (256 * 1024)                             // bf16 [8192][1024]
#define O_WCAT (O_XB + (size_t)T_TOK * H_DIM * 2)       // bf16 [8][8192][1024]
#define O_WOUT (O_WCAT + (size_t)N_EXP * N_CAT * H_DIM * 2) // bf16 [8][1024][4096]
#define O_G    (O_WOUT + (size_t)N_EXP * I_DIM * H_DIM * 2) // bf16 [144*128][4096]
#define O_OS   O_WCAT   // f32 [16384][1024]; aliases Wcat (dead after gemm1)
// total ≈ 352.3 MiB

// meta: [0]=tileCount, [16..160)=tileExpert, [160..304)=rowStart,
// [304..448)=rowEnd, [448..456)=cursors

// LDS chunk swizzle: s(r) = (r>>1)&3.  With 64-B rows, even rows live in
// banks 0-15, odd in 16-31; s(r)=(r&3) only produced chunks {0,2} on even
// rows (2-way conflict, measured 3.4e7).  (r>>1)&3 walks 0,1,2,3 across
// even rows -> each 8-lane group covers all 32 banks exactly once.
#define SWZ(r) (((r) >> 1) & 3)

__device__ __forceinline__ u16 f2bf(float f) {
  union { float f; unsigned u; } v; v.f = f;
  unsigned r = v.u + 0x7FFFu + ((v.u >> 16) & 1u);   // RNE
  return (u16)(r >> 16);
}

#define GLL(g, l) __builtin_amdgcn_global_load_lds( \
    (const __attribute__((address_space(1))) void*)(g), \
    (__attribute__((address_space(3))) void*)(l), 16, 0, 0)

#define MFMA16(a, b, c) __builtin_amdgcn_mfma_f32_16x16x32_bf16(a, b, c, 0, 0, 0)

__global__ void route_count(const int* __restrict__ sel, int* __restrict__ meta) {
  __shared__ int cnt[N_EXP];
  const int tid = threadIdx.x;
  if (tid < N_EXP) cnt[tid] = 0;
  __syncthreads();
  for (int i = tid; i < NSLOT; i += 256) atomicAdd(&cnt[sel[i]], 1);
  __syncthreads();
  if (tid == 0) {
    int run = 0, tc = 0;
    for (int e = 0; e < N_EXP; ++e) {
      const int c = cnt[e];
      meta[448 + e] = run;
      const int nt = (c + 127) >> 7;
      for (int t = 0; t < nt; ++t) {
        meta[16 + tc] = e;
        meta[160 + tc] = run + t * 128;
        int end = run + t * 128 + 128;
        if (end > run + c) end = run + c;
        meta[304 + tc] = end;
        ++tc;
      }
      run += c;
    }
    meta[0] = tc;
  }
}

__global__ void route_fill(const int* __restrict__ sel, const float* __restrict__ rw,
                           int* __restrict__ meta, int* __restrict__ etok,
                           float* __restrict__ ew, int* __restrict__ inv) {
  const int i = blockIdx.x * 256 + threadIdx.x;
  if (i >= NSLOT) return;
  const int e = sel[i];
  const int pos = atomicAdd(&meta[448 + e], 1);
  etok[pos] = i >> 1;      // token id (K=2)
  ew[pos] = rw[i];
  inv[i] = pos;
}

__global__ void conv_x(const float* __restrict__ x, u16* __restrict__ xb) {
  const size_t i = ((size_t)blockIdx.x * 256 + threadIdx.x) * 4;
  const float4 v = *(const float4*)&x[i];
  u16x4 o;
  o.x = f2bf(v.x); o.y = f2bf(v.y); o.z = f2bf(v.z); o.w = f2bf(v.w);
  *(u16x4*)&xb[i] = o;
}

// src [nmat][R][C] f32 -> transpose+convert to bf16.
// mode 0: Wi -> Wcat row ((c>>4)<<5)|(c&15)         (dst [nmat][2C][R])
// mode 1: Wv -> Wcat row ((c>>4)<<5)|16|(c&15)
// mode 2: plain transpose (dst [nmat][C][R])
__global__ void transp_conv(const float* __restrict__ src, u16* __restrict__ dst,
                            int R, int C, int mode) {
  __shared__ float t[64][65];
  const int tid = threadIdx.x;
  const int mat = blockIdx.z;
  const int rb = blockIdx.y * 64, cb = blockIdx.x * 64;
  const float* s = src + (size_t)mat * R * C + (size_t)rb * C + cb;
#pragma unroll
  for (int it = 0; it < 4; ++it) {
    const int r = it * 16 + (tid >> 4);
    const int c = (tid & 15) * 4;
    const float4 v = *(const float4*)&s[(size_t)r * C + c];
    t[r][c] = v.x; t[r][c + 1] = v.y; t[r][c + 2] = v.z; t[r][c + 3] = v.w;
  }
  __syncthreads();
  const size_t dstride = (mode == 2) ? (size_t)R * C : 2 * (size_t)R * C;
  u16* dd = dst + (size_t)mat * dstride;
#pragma unroll
  for (int it = 0; it < 2; ++it) {
    const int ocl = it * 32 + (tid >> 3);
    const int oc = cb + ocl;
    const int mrow = (mode == 2) ? oc : (((oc >> 4) << 5) | (mode << 4) | (oc & 15));
    const int j0 = (tid & 7) * 8;
    u16x8 o;
#pragma unroll
    for (int j = 0; j < 8; ++j) o[j] = f2bf(t[j0 + j][oc - cb]);
    *(u16x8*)&dd[(size_t)mrow * R + rb + j0] = o;
  }
}

// GEMM1: C = Xg @ Wcat^T-layout, 128x128 tile, BK=32; epilogue pairs
// (even,odd) 16-col blocks -> G = gelu(ci)*cv  [tile*128+row][I_DIM]
__global__ __launch_bounds__(256) void gemm1(
    const u16* __restrict__ Xb, const u16* __restrict__ Wc,
    u16* __restrict__ Gout, const int* __restrict__ meta,
    const int* __restrict__ etok) {
  const int tile = blockIdx.y;
  if (tile >= meta[0]) return;
  const int e  = meta[16 + tile];
  const int r0 = meta[160 + tile];
  const int r1 = meta[304 + tile];
  const int n0 = blockIdx.x << 7;   // over N_CAT=8192

  __shared__ __align__(16) u16 As[2][4096];
  __shared__ __align__(16) u16 Bs[2][4096];

  const int tid = threadIdx.x;
  const int t0 = tid, t1 = tid + 256;
  const int rA0 = t0 >> 2, rA1 = t1 >> 2;
  const int sc0 = ((t0 & 3) ^ SWZ(rA0)) << 3;   // source-chunk swizzle (elems)
  const int sc1 = ((t1 & 3) ^ SWZ(rA1)) << 3;
  int ia0 = r0 + rA0; if (ia0 >= r1) ia0 = r0;
  int ia1 = r0 + rA1; if (ia1 >= r1) ia1 = r0;
  const u16* gA0 = Xb + (size_t)etok[ia0] * H_DIM + sc0;
  const u16* gA1 = Xb + (size_t)etok[ia1] * H_DIM + sc1;
  const u16* gB0 = Wc + ((size_t)e * N_CAT + n0 + rA0) * H_DIM + sc0;
  const u16* gB1 = Wc + ((size_t)e * N_CAT + n0 + rA1) * H_DIM + sc1;

  const int lane = tid & 63;
  const int wid = tid >> 6;
  const int wm = (wid >> 1) << 6, wn = (wid & 1) << 6;
  const int lr = lane & 15, q = lane >> 4;
  const int cq = (q ^ SWZ(lr)) << 3;   // row%16 == lr, and (row>>1)&3 == (lr>>1)&3
  int aoff[4], boff[4];
#pragma unroll
  for (int i = 0; i < 4; ++i) {
    aoff[i] = (wm + i * 16 + lr) * 32 + cq;
    boff[i] = (wn + i * 16 + lr) * 32 + cq;
  }

  f32x4 c[4][4];
#pragma unroll
  for (int i = 0; i < 4; ++i)
#pragma unroll
    for (int j = 0; j < 4; ++j) c[i][j] = (f32x4)0.0f;

#define STAGE1(b, kt) do { const int ko = (kt) << 5;                  \
    GLL(gA0 + ko, &As[b][t0 * 8]); GLL(gA1 + ko, &As[b][t1 * 8]);     \
    GLL(gB0 + ko, &Bs[b][t0 * 8]); GLL(gB1 + ko, &Bs[b][t1 * 8]); } while (0)

  STAGE1(0, 0);
  __syncthreads();
  int buf = 0;
  for (int kt = 0; kt < H_DIM / 32; ++kt) {
    if (kt + 1 < H_DIM / 32) STAGE1(buf ^ 1, kt + 1);
    short8 a[4], b_[4];
#pragma unroll
    for (int i = 0; i < 4; ++i) a[i] = *(const short8*)&As[buf][aoff[i]];
#pragma unroll
    for (int j = 0; j < 4; ++j) b_[j] = *(const short8*)&Bs[buf][boff[j]];
#pragma unroll
    for (int i = 0; i < 4; ++i)
#pragma unroll
      for (int j = 0; j < 4; ++j) c[i][j] = MFMA16(a[i], b_[j], c[i][j]);
    __syncthreads();
    buf ^= 1;
  }

  // epilogue: j-tile pairs (2p, 2p+1) = (Wi, Wv) for G col gcb + p*16 + lr
  // gelu(x)*v = x*(1 - rcp(exp2(c1*(x+0.044715x^3)) + 1))*v
  //   c1 = 2*0.7978845608*log2(e); rcp avoids the slow full-precision divide.
  u16* gb = Gout + (size_t)tile * 128 * I_DIM;
  const int gcb = (n0 + wn) >> 1;
#pragma unroll
  for (int i = 0; i < 4; ++i)
#pragma unroll
    for (int t = 0; t < 4; ++t) {
      const int row = wm + i * 16 + q * 4 + t;
      u16* grow = gb + (size_t)row * I_DIM + gcb + lr;
#pragma unroll
      for (int p = 0; p < 2; ++p) {
        const float x = c[i][2 * p][t];
        const float v = c[i][2 * p + 1][t];
        const float u2l = 2.3022082f * (x + 0.044715f * x * x * x);
        const float texp = __builtin_amdgcn_exp2f(u2l);
        const float r = __builtin_amdgcn_rcpf(texp + 1.0f);
        grow[p * 16] = f2bf((x - x * r) * v);
      }
    }
}

// GEMM2: Os[slot] = G @ W_out^T', 128x128 tile, BK=32, plain f32 stores
__global__ __launch_bounds__(256) void gemm2(
    const u16* __restrict__ Gin, const u16* __restrict__ Wo,
    float* __restrict__ Os, const int* __restrict__ meta) {
  const int tile = blockIdx.y;
  if (tile >= meta[0]) return;
  const int e  = meta[16 + tile];
  const int r0 = meta[160 + tile];
  const int r1 = meta[304 + tile];
  const int n0 = blockIdx.x << 7;

  __shared__ __align__(16) u16 As[2][4096];
  __shared__ __align__(16) u16 Bs[2][4096];

  const int tid = threadIdx.x;
  const int t0 = tid, t1 = tid + 256;
  const int rA0 = t0 >> 2, rA1 = t1 >> 2;
  const int sc0 = ((t0 & 3) ^ SWZ(rA0)) << 3;
  const int sc1 = ((t1 & 3) ^ SWZ(rA1)) << 3;
  const u16* gA0 = Gin + ((size_t)tile * 128 + rA0) * I_DIM + sc0;
  const u16* gA1 = Gin + ((size_t)tile * 128 + rA1) * I_DIM + sc1;
  const size_t wb = (size_t)e * H_DIM * I_DIM;
  const u16* gB0 = Wo + wb + (size_t)(n0 + rA0) * I_DIM + sc0;
  const u16* gB1 = Wo + wb + (size_t)(n0 + rA1) * I_DIM + sc1;

  const int lane = tid & 63;
  const int wid = tid >> 6;
  const int wm = (wid >> 1) << 6, wn = (wid & 1) << 6;
  const int lr = lane & 15, q = lane >> 4;
  const int cq = (q ^ SWZ(lr)) << 3;
  int aoff[4], boff[4];
#pragma unroll
  for (int i = 0; i < 4; ++i) {
    aoff[i] = (wm + i * 16 + lr) * 32 + cq;
    boff[i] = (wn + i * 16 + lr) * 32 + cq;
  }

  f32x4 c[4][4];
#pragma unroll
  for (int i = 0; i < 4; ++i)
#pragma unroll
    for (int j = 0; j < 4; ++j) c[i][j] = (f32x4)0.0f;

#define STAGE2(b, kt) do { const int ko = (kt) << 5;                  \
    GLL(gA0 + ko, &As[b][t0 * 8]); GLL(gA1 + ko, &As[b][t1 * 8]);     \
    GLL(gB0 + ko, &Bs[b][t0 * 8]); GLL(gB1 + ko, &Bs[b][t1 * 8]); } while (0)

  STAGE2(0, 0);
  __syncthreads();
  int buf = 0;
  for (int kt = 0; kt < I_DIM / 32; ++kt) {
    if (kt + 1 < I_DIM / 32) STAGE2(buf ^ 1, kt + 1);
    short8 a[4], b_[4];
#pragma unroll
    for (int i = 0; i < 4; ++i) a[i] = *(const short8*)&As[buf][aoff[i]];
#pragma unroll
    for (int j = 0; j < 4; ++j) b_[j] = *(const short8*)&Bs[buf][boff[j]];
#pragma unroll
    for (int i = 0; i < 4; ++i)
#pragma unroll
      for (int j = 0; j < 4; ++j) c[i][j] = MFMA16(a[i], b_[j], c[i][j]);
    __syncthreads();
    buf ^= 1;
  }

#pragma unroll
  for (int i = 0; i < 4; ++i)
#pragma unroll
    for (int t = 0; t < 4; ++t) {
      const int row = wm + i * 16 + q * 4 + t;
      const int gp = r0 + row;
      if (gp < r1) {
        float* orow = Os + (size_t)gp * H_DIM + n0 + wn + lr;
#pragma unroll
        for (int j = 0; j < 4; ++j) orow[j * 16] = c[i][j][t];
      }
    }
}

// out[t] = w0*Os[p0] + w1*Os[p1]; one block per token
__global__ void combine(const float* __restrict__ Os, const int* __restrict__ inv,
                        const float* __restrict__ ew, float* __restrict__ out) {
  const int t = blockIdx.x;
  const int c4 = threadIdx.x * 4;
  const int p0 = inv[2 * t], p1 = inv[2 * t + 1];
  const float w0 = ew[p0], w1 = ew[p1];
  const float4 a = *(const float4*)&Os[(size_t)p0 * H_DIM + c4];
  const float4 b = *(const float4*)&Os[(size_t)p1 * H_DIM + c4];
  float4 o;
  o.x = w0 * a.x + w1 * b.x;
  o.y = w0 * a.y + w1 * b.y;
  o.z = w0 * a.z + w1 * b.z;
  o.w = w0 * a.w + w1 * b.w;
  *(float4*)&out[(size_t)t * H_DIM + c4] = o;
}

extern "C" void kernel_launch(void* const* d_in, const int* in_sizes, int n_in,
                              void* d_out, int out_size, void* d_ws, size_t ws_size,
                              hipStream_t stream) {
  const float* hs    = (const float*)d_in[0];
  const float* rw    = (const float*)d_in[1];
  const int*   sel   = (const int*)d_in[2];
  const float* w_in  = (const float*)d_in[3];
  const float* w_v   = (const float*)d_in[4];
  const float* w_out = (const float*)d_in[5];
  float* out = (float*)d_out;
  char* ws = (char*)d_ws;
  int* meta   = (int*)(ws + O_META);
  int* etok   = (int*)(ws + O_ETOK);
  float* ew   = (float*)(ws + O_EW);
  int* inv    = (int*)(ws + O_INV);
  u16* xb     = (u16*)(ws + O_XB);
  u16* wcat   = (u16*)(ws + O_WCAT);
  u16* wo     = (u16*)(ws + O_WOUT);
  u16* g      = (u16*)(ws + O_G);
  float* os   = (float*)(ws + O_OS);

  route_count<<<1, 256, 0, stream>>>(sel, meta);
  route_fill<<<NSLOT / 256, 256, 0, stream>>>(sel, rw, meta, etok, ew, inv);
  conv_x<<<(T_TOK * H_DIM / 4) / 256, 256, 0, stream>>>(hs, xb);
  transp_conv<<<dim3(I_DIM / 64, H_DIM / 64, N_EXP), 256, 0, stream>>>(w_in, wcat, H_DIM, I_DIM, 0);
  transp_conv<<<dim3(I_DIM / 64, H_DIM / 64, N_EXP), 256, 0, stream>>>(w_v, wcat, H_DIM, I_DIM, 1);
  transp_conv<<<dim3(H_DIM / 64, I_DIM / 64, N_EXP), 256, 0, stream>>>(w_out, wo, I_DIM, H_DIM, 2);
  gemm1<<<dim3(N_CAT / 128, MAXTILES), 256, 0, stream>>>(xb, wcat, g, meta, etok);
  gemm2<<<dim3(H_DIM / 128, MAXTILES), 256, 0, stream>>>(g, wo, os, meta);
  combine<<<T_TOK, 256, 0, stream>>>(os, inv, ew, out);
}